// Round 1
// baseline (194.943 us; speedup 1.0000x reference)
//
#include <hip/hip_runtime.h>

// InternalInteraction: out[b,j,d] = sum_i [ relu((x_i*x_j)@W1^T + b1) @ W2^T + b2 ]
// Factored: hsum[b,j,h] = sum_i relu((x_i*x_j)@W1^T + b1); out = hsum@W2^T + 16*b2.
// B=2048, A=16, D=128, H=512. Storage fp32; MFMA in bf16.
//
// Round-4 structure (vs round-3):
//  - ALL 16 pair tiles built up front into a 68 KB LDS region (1 barrier),
//    then the GEMM1 i-loop runs with ZERO barriers: each wave streams
//    512 MFMAs with hand-pipelined A-fragment double-buffering.
//    (Round-3 had 16 per-i barriers -> latency-serialized at 2 blocks/CU.)
//  - x staged in LDS as f32 (no cvt chain in build; single-rounded product)
//  - hs (GEMM2 staging) aliases the dead ps region -> LDS 78 KB, 2 blocks/CU
//  - barriers per block: 18 -> 4

#define BATCH 2048
#define AA 16
#define DD 128
#define HH 512

typedef __bf16 bf16;
typedef bf16  bf16x4 __attribute__((ext_vector_type(4)));
typedef bf16  bf16x8 __attribute__((ext_vector_type(8)));
typedef float f32x4  __attribute__((ext_vector_type(4)));

__device__ inline f32x4 splat4(float v) { f32x4 r = {v, v, v, v}; return r; }

// ---- prologue: fp32 -> bf16 weight conversion into d_ws ----
// ws layout: [0, 65536)  = W1b (512x128 row-major bf16)
//            [65536, ..) = W2b (128x512 row-major bf16)
__global__ __launch_bounds__(256, 1)
void convert_weights(const float* __restrict__ W1,
                     const float* __restrict__ W2,
                     bf16* __restrict__ wsb)
{
    int t = blockIdx.x * 256 + threadIdx.x;      // 0..32767, 4 elems each
    f32x4 v = (t < 16384) ? *(const f32x4*)(W1 + 4 * t)
                          : *(const f32x4*)(W2 + 4 * (t - 16384));
    bf16x4 o;
    o[0] = (bf16)v[0]; o[1] = (bf16)v[1]; o[2] = (bf16)v[2]; o[3] = (bf16)v[3];
    *(bf16x4*)(wsb + 4 * t) = o;
}

// One block per batch. 256 threads = 4 waves; wave w owns H cols [w*128, w*128+128).
__global__ __launch_bounds__(256, 2)
void interact_kernel(const float* __restrict__ x,    // [B, A, D] fp32
                     const bf16*  __restrict__ W1b,  // [H, D] bf16 (from ws)
                     const float* __restrict__ b1,   // [H]
                     const bf16*  __restrict__ W2b,  // [D, H] bf16 (from ws)
                     const float* __restrict__ b2,   // [D]
                     float* __restrict__ out)        // [B, A, D] fp32
{
    // xs: x_b in f32, row stride 136 (544 B = 34*16 -> aligned, odd*16 banks)
    __shared__ float xs[16][136];                               // 8704 B
    // ps: all 16 pair tiles [i][j][d], stride 136 bf16 (272 B). 69632 B.
    // hs: GEMM2 staging [16][520] bf16 (16640 B) -- ALIASES ps (dead by then).
    __shared__ __align__(16) unsigned char smem_raw[16 * 16 * 136 * 2];
    bf16 (*ps)[16][136] = reinterpret_cast<bf16(*)[16][136]>(smem_raw);
    bf16 (*hs)[520]     = reinterpret_cast<bf16(*)[520]>(smem_raw);

    const int b    = blockIdx.x;
    const int tid  = threadIdx.x;
    const int wave = tid >> 6;
    const int lane = tid & 63;
    const int quad = lane >> 4;   // 0..3
    const int col  = lane & 15;   // 0..15

    // build-phase coordinates: thread owns (jrow, d0..d0+8)
    const int jrow = tid >> 4;          // 0..15
    const int d0   = (tid & 15) * 8;    // 0..120

    // ---- stage x_b into LDS (f32) and keep own slice in regs ----
    f32x4 xlo, xhi;
    {
        const float* src = x + (size_t)b * (AA * DD) + jrow * DD + d0;
        xlo = *(const f32x4*)src;
        xhi = *(const f32x4*)(src + 4);
        *(f32x4*)(&xs[jrow][d0])     = xlo;
        *(f32x4*)(&xs[jrow][d0 + 4]) = xhi;
    }

    // ---- W1 fragments, register-resident (8n x 4kk x 16B = 128 VGPRs) ----
    // B-operand layout: lane holds B[k = quad*8+e + kk*32][n-col], row-major [N,K].
    bf16x8 w1f[8][4];
    float  b1f[8];
#pragma unroll
    for (int n = 0; n < 8; ++n) {
        int h  = wave * 128 + n * 16 + col;
        b1f[n] = b1[h];
#pragma unroll
        for (int kk = 0; kk < 4; ++kk)
            w1f[n][kk] = *(const bf16x8*)(W1b + h * DD + kk * 32 + quad * 8);
    }

    f32x4 hsum[8];
#pragma unroll
    for (int n = 0; n < 8; ++n) hsum[n] = splat4(0.f);

    __syncthreads();   // xs complete

    // ---- build ALL 16 pair tiles: ps[i][j][d] = bf16(x_i[d] * x_j[d]) ----
#pragma unroll 4
    for (int i = 0; i < 16; ++i) {
        f32x4 alo = *(f32x4*)(&xs[i][d0]);
        f32x4 ahi = *(f32x4*)(&xs[i][d0 + 4]);
        bf16x8 pr;
#pragma unroll
        for (int e = 0; e < 4; ++e) pr[e]     = (bf16)(alo[e] * xlo[e]);
#pragma unroll
        for (int e = 0; e < 4; ++e) pr[4 + e] = (bf16)(ahi[e] * xhi[e]);
        *(bf16x8*)(&ps[i][jrow][d0]) = pr;
    }
    __syncthreads();   // all pair tiles ready; no more barriers until GEMM2

    // ---- barrier-free GEMM1 stream: hand-pipelined A-fragment dbuf ----
    // A-operand: lane holds A[row=col][k=quad*8+e (+32*kk)] from ps[i].
    bf16x8 afA[4], afB[4];
#pragma unroll
    for (int kk = 0; kk < 4; ++kk)
        afA[kk] = *(bf16x8*)(&ps[0][col][kk * 32 + quad * 8]);

    for (int i = 0; i < 16; i += 2) {
        // -- body A: prefetch i+1, MFMA on afA, relu-accumulate --
#pragma unroll
        for (int kk = 0; kk < 4; ++kk)
            afB[kk] = *(bf16x8*)(&ps[i + 1][col][kk * 32 + quad * 8]);
        {
            f32x4 acc[8];
#pragma unroll
            for (int n = 0; n < 8; ++n)
                acc[n] = __builtin_amdgcn_mfma_f32_16x16x32_bf16(
                    afA[0], w1f[n][0], splat4(b1f[n]), 0, 0, 0);
#pragma unroll
            for (int kk = 1; kk < 4; ++kk)
#pragma unroll
                for (int n = 0; n < 8; ++n)
                    acc[n] = __builtin_amdgcn_mfma_f32_16x16x32_bf16(
                        afA[kk], w1f[n][kk], acc[n], 0, 0, 0);
#pragma unroll
            for (int n = 0; n < 8; ++n)
#pragma unroll
                for (int r = 0; r < 4; ++r)
                    hsum[n][r] += fmaxf(acc[n][r], 0.f);
        }

        // -- body B: prefetch i+2 (wraps harmlessly at tail), MFMA on afB --
        const int inext = (i + 2) & 15;
#pragma unroll
        for (int kk = 0; kk < 4; ++kk)
            afA[kk] = *(bf16x8*)(&ps[inext][col][kk * 32 + quad * 8]);
        {
            f32x4 acc[8];
#pragma unroll
            for (int n = 0; n < 8; ++n)
                acc[n] = __builtin_amdgcn_mfma_f32_16x16x32_bf16(
                    afB[0], w1f[n][0], splat4(b1f[n]), 0, 0, 0);
#pragma unroll
            for (int kk = 1; kk < 4; ++kk)
#pragma unroll
                for (int n = 0; n < 8; ++n)
                    acc[n] = __builtin_amdgcn_mfma_f32_16x16x32_bf16(
                        afB[kk], w1f[n][kk], acc[n], 0, 0, 0);
#pragma unroll
            for (int n = 0; n < 8; ++n)
#pragma unroll
                for (int r = 0; r < 4; ++r)
                    hsum[n][r] += fmaxf(acc[n][r], 0.f);
        }
    }

    __syncthreads();   // all ps reads done before hs overwrites the region

    // ---- hsum -> LDS (bf16) for GEMM2 A-operand re-layout ----
    // C/D layout: row j = quad*4+r, col = lane&15 (h-col = wave*128+n*16+col)
#pragma unroll
    for (int n = 0; n < 8; ++n)
#pragma unroll
        for (int r = 0; r < 4; ++r)
            hs[quad * 4 + r][wave * 128 + n * 16 + col] = (bf16)hsum[n][r];

    __syncthreads();

    // ---- GEMM2: out[j,d] = hsum[j,:] @ W2^T + 16*b2 ----
    // M=16 (j), N=32 per wave (d), K=512 (h). W2b is [D,H] row-major.
    f32x4 acc2[2];
#pragma unroll
    for (int n2 = 0; n2 < 2; ++n2)
        acc2[n2] = splat4(16.f * b2[wave * 32 + n2 * 16 + col]);

#pragma unroll
    for (int ks = 0; ks < 16; ++ks) {
        int h0 = ks * 32 + quad * 8;
        bf16x8 a2 = *(bf16x8*)(&hs[col][h0]);
#pragma unroll
        for (int n2 = 0; n2 < 2; ++n2) {
            int d = wave * 32 + n2 * 16 + col;
            bf16x8 bw = *(const bf16x8*)(W2b + d * HH + h0);
            acc2[n2] = __builtin_amdgcn_mfma_f32_16x16x32_bf16(
                a2, bw, acc2[n2], 0, 0, 0);
        }
    }

#pragma unroll
    for (int n2 = 0; n2 < 2; ++n2)
#pragma unroll
        for (int r = 0; r < 4; ++r) {
            int j = quad * 4 + r;
            int d = wave * 32 + n2 * 16 + col;
            out[(size_t)b * (AA * DD) + j * DD + d] = acc2[n2][r];
        }
}

extern "C" void kernel_launch(void* const* d_in, const int* in_sizes, int n_in,
                              void* d_out, int out_size, void* d_ws, size_t ws_size,
                              hipStream_t stream)
{
    const float* x  = (const float*)d_in[0];  // [2048,16,128]
    const float* W1 = (const float*)d_in[1];  // [512,128]
    const float* b1 = (const float*)d_in[2];  // [512]
    const float* W2 = (const float*)d_in[3];  // [128,512]
    const float* b2 = (const float*)d_in[4];  // [128]
    float* out = (float*)d_out;

    bf16* wsb = (bf16*)d_ws;                  // 256 KB used
    convert_weights<<<128, 256, 0, stream>>>(W1, W2, wsb);

    const bf16* W1b = wsb;
    const bf16* W2b = wsb + (size_t)HH * DD;
    interact_kernel<<<BATCH, 256, 0, stream>>>(x, W1b, b1, W2b, b2, out);
}

// Round 2
// 148.102 us; speedup vs baseline: 1.3163x; 1.3163x over previous
//
#include <hip/hip_runtime.h>

// InternalInteraction: out[b,j,d] = sum_i [ relu((x_i*x_j)@W1^T + b1) @ W2^T + b2 ]
// Factored: hsum[b,j,h] = sum_i relu((x_i*x_j)@W1^T + b1); out = hsum@W2^T + 16*b2.
// B=2048, A=16, D=128, H=512. Storage fp32; MFMA in bf16.
//
// Round-5 structure (vs round-4):
//  - POST-MORTEM r4: hand-pipelined A-frag dbuf spilled to scratch
//    (WRITE_SIZE 16->48 MB) -> 50% regression. Reverted to plain per-i loads.
//  - Occupancy tier jump: 512-thread blocks, 8 waves, each wave owns 64
//    h-cols (w1f = 64 VGPRs instead of 128). In-loop live set ~120 regs
//    -> <=128 tier -> 4 waves/SIMD -> 16 waves/CU (was 8). This is the
//    latency-bound kernel's main lever; __launch_bounds__(512,4) pins it.
//  - Keep: all 16 pair tiles built up front (1 barrier), barrier-free
//    GEMM1 stream, f32 xs staging, hs aliasing the dead ps region.
//  - 4 barriers/block total.

#define BATCH 2048
#define AA 16
#define DD 128
#define HH 512

typedef __bf16 bf16;
typedef bf16  bf16x4 __attribute__((ext_vector_type(4)));
typedef bf16  bf16x8 __attribute__((ext_vector_type(8)));
typedef float f32x4  __attribute__((ext_vector_type(4)));

__device__ inline f32x4 splat4(float v) { f32x4 r = {v, v, v, v}; return r; }

// ---- prologue: fp32 -> bf16 weight conversion into d_ws ----
// ws layout: [0, 65536)  = W1b (512x128 row-major bf16)
//            [65536, ..) = W2b (128x512 row-major bf16)
__global__ __launch_bounds__(256, 1)
void convert_weights(const float* __restrict__ W1,
                     const float* __restrict__ W2,
                     bf16* __restrict__ wsb)
{
    int t = blockIdx.x * 256 + threadIdx.x;      // 0..32767, 4 elems each
    f32x4 v = (t < 16384) ? *(const f32x4*)(W1 + 4 * t)
                          : *(const f32x4*)(W2 + 4 * (t - 16384));
    bf16x4 o;
    o[0] = (bf16)v[0]; o[1] = (bf16)v[1]; o[2] = (bf16)v[2]; o[3] = (bf16)v[3];
    *(bf16x4*)(wsb + 4 * t) = o;
}

// One block per batch. 512 threads = 8 waves; wave w owns H cols [w*64, w*64+64).
__global__ __launch_bounds__(512, 4)
void interact_kernel(const float* __restrict__ x,    // [B, A, D] fp32
                     const bf16*  __restrict__ W1b,  // [H, D] bf16 (from ws)
                     const float* __restrict__ b1,   // [H]
                     const bf16*  __restrict__ W2b,  // [D, H] bf16 (from ws)
                     const float* __restrict__ b2,   // [D]
                     float* __restrict__ out)        // [B, A, D] fp32
{
    // xs: x_b in f32, row stride 136 (544 B) -> staged once, read in build
    __shared__ float xs[16][136];                               // 8704 B
    // ps: all 16 pair tiles [i][j][136] bf16, row stride 272 B (odd*16B ->
    //     A-frag b128 reads land on the 8-slot all-bank pattern). 69632 B.
    // hs: GEMM2 staging [16][520] bf16 (16640 B) -- ALIASES ps (dead by then).
    __shared__ __align__(16) unsigned char smem_raw[16 * 16 * 136 * 2];
    bf16 (*ps)[16][136] = reinterpret_cast<bf16(*)[16][136]>(smem_raw);
    bf16 (*hs)[520]     = reinterpret_cast<bf16(*)[520]>(smem_raw);

    const int b    = blockIdx.x;
    const int tid  = threadIdx.x;
    const int wave = tid >> 6;    // 0..7
    const int lane = tid & 63;
    const int quad = lane >> 4;   // 0..3
    const int col  = lane & 15;   // 0..15

    // build-phase coordinates: thread owns (jrow, dq..dq+4)
    const int jrow = tid >> 5;          // 0..15
    const int dq   = (tid & 31) * 4;    // 0..124

    // ---- stage x_b into LDS (f32); keep own 4-float slice in regs ----
    f32x4 xj;
    {
        const float* src = x + (size_t)b * (AA * DD) + jrow * DD + dq;
        xj = *(const f32x4*)src;
        *(f32x4*)(&xs[jrow][dq]) = xj;
    }

    // ---- W1 fragments, register-resident (4n x 4kk x 16B = 64 VGPRs) ----
    // B-operand layout: lane holds B[k = quad*8+e + kk*32][n-col], row-major [N,K].
    bf16x8 w1f[4][4];
    float  b1f[4];
#pragma unroll
    for (int n = 0; n < 4; ++n) {
        int h  = wave * 64 + n * 16 + col;
        b1f[n] = b1[h];
#pragma unroll
        for (int kk = 0; kk < 4; ++kk)
            w1f[n][kk] = *(const bf16x8*)(W1b + h * DD + kk * 32 + quad * 8);
    }

    f32x4 hsum[4];
#pragma unroll
    for (int n = 0; n < 4; ++n) hsum[n] = splat4(0.f);

    __syncthreads();   // xs complete

    // ---- build ALL 16 pair tiles: ps[i][j][d] = bf16(x_i[d] * x_j[d]) ----
#pragma unroll 4
    for (int i = 0; i < 16; ++i) {
        f32x4 xi = *(f32x4*)(&xs[i][dq]);
        bf16x4 pr;
#pragma unroll
        for (int e = 0; e < 4; ++e) pr[e] = (bf16)(xj[e] * xi[e]);
        *(bf16x4*)(&ps[i][jrow][dq]) = pr;
    }
    __syncthreads();   // all pair tiles ready; no barriers until GEMM2 staging

    // ---- barrier-free GEMM1 stream; plain per-i loads, compiler-scheduled ----
    // A-operand: lane holds A[row=col][k=quad*8+e (+32*kk)] from ps[i].
#pragma unroll 1
    for (int i = 0; i < 16; ++i) {
        bf16x8 af[4];
#pragma unroll
        for (int kk = 0; kk < 4; ++kk)
            af[kk] = *(bf16x8*)(&ps[i][col][kk * 32 + quad * 8]);

        f32x4 acc[4];
#pragma unroll
        for (int n = 0; n < 4; ++n)
            acc[n] = __builtin_amdgcn_mfma_f32_16x16x32_bf16(
                af[0], w1f[n][0], splat4(b1f[n]), 0, 0, 0);
#pragma unroll
        for (int kk = 1; kk < 4; ++kk)
#pragma unroll
            for (int n = 0; n < 4; ++n)
                acc[n] = __builtin_amdgcn_mfma_f32_16x16x32_bf16(
                    af[kk], w1f[n][kk], acc[n], 0, 0, 0);

        // relu + accumulate (C/D layout: row j = quad*4+r, col = lane&15)
#pragma unroll
        for (int n = 0; n < 4; ++n)
#pragma unroll
            for (int r = 0; r < 4; ++r)
                hsum[n][r] += fmaxf(acc[n][r], 0.f);
    }

    __syncthreads();   // all ps reads done before hs overwrites the region

    // ---- hsum -> LDS (bf16) for GEMM2 A-operand re-layout ----
    // C/D layout: row j = quad*4+r, h-col = wave*64 + n*16 + col
#pragma unroll
    for (int n = 0; n < 4; ++n)
#pragma unroll
        for (int r = 0; r < 4; ++r)
            hs[quad * 4 + r][wave * 64 + n * 16 + col] = (bf16)hsum[n][r];

    __syncthreads();

    // ---- GEMM2: out[j,d] = hsum[j,:] @ W2^T + 16*b2 ----
    // M=16 (j), N=16 per wave (d = wave*16 + col), K=512 (h). W2b is [D,H].
    const int d = wave * 16 + col;
    f32x4 acc2 = splat4(16.f * b2[d]);

#pragma unroll
    for (int ks = 0; ks < 16; ++ks) {
        int h0 = ks * 32 + quad * 8;
        bf16x8 a2 = *(bf16x8*)(&hs[col][h0]);
        bf16x8 bw = *(const bf16x8*)(W2b + d * HH + h0);
        acc2 = __builtin_amdgcn_mfma_f32_16x16x32_bf16(a2, bw, acc2, 0, 0, 0);
    }

#pragma unroll
    for (int r = 0; r < 4; ++r) {
        int j = quad * 4 + r;
        out[(size_t)b * (AA * DD) + j * DD + d] = acc2[r];
    }
}

extern "C" void kernel_launch(void* const* d_in, const int* in_sizes, int n_in,
                              void* d_out, int out_size, void* d_ws, size_t ws_size,
                              hipStream_t stream)
{
    const float* x  = (const float*)d_in[0];  // [2048,16,128]
    const float* W1 = (const float*)d_in[1];  // [512,128]
    const float* b1 = (const float*)d_in[2];  // [512]
    const float* W2 = (const float*)d_in[3];  // [128,512]
    const float* b2 = (const float*)d_in[4];  // [128]
    float* out = (float*)d_out;

    bf16* wsb = (bf16*)d_ws;                  // 256 KB used
    convert_weights<<<128, 256, 0, stream>>>(W1, W2, wsb);

    const bf16* W1b = wsb;
    const bf16* W2b = wsb + (size_t)HH * DD;
    interact_kernel<<<BATCH, 512, 0, stream>>>(x, W1b, b1, W2b, b2, out);
}